// Round 5
// baseline (236.338 us; speedup 1.0000x reference)
//
#include <hip/hip_runtime.h>
#include <stdint.h>

// QuantizedConv2d int8 implicit GEMM via MFMA i32_16x16x64_i8.
// N=32, C_in=128, H=W=56, C_out=256, 3x3, pad 1, stride 1.
// Output int8 values stored as int32 (harness reads integer outputs as np.int32).
//
// R5: (1) wave = 64 M x 64 co (2x MFMA per staged/loaded byte, 288 MFMA/wave,
// block-rounds 6->3); (2) all prep fused into ONE kernel (pack_x vectorized,
// weight pack + BG = bias - zp*SC per border class); 2 dispatches total.

#define NB 32
#define CI 128
#define HH 56
#define WW 56
#define CO 256
#define SPA (HH * WW)            // 3136; 64 | 3136 -> wave tiles never cross n
#define XP_BYTES (NB * SPA * CI) // 12845056
#define BP_BYTES (9 * 2 * 4 * 4 * 64 * 16) // 294912

typedef int v4i __attribute__((ext_vector_type(4)));

// ---- prep: blocks [0,1792): pack x; blocks [1792,2048): pack w + BG ----
__global__ __launch_bounds__(256) void prep_kernel(
    const int* __restrict__ x, const int* __restrict__ wgt,
    const int* __restrict__ bias, const int* __restrict__ zpi,
    int8_t* __restrict__ xp, int8_t* __restrict__ bp, int* __restrict__ BG)
{
    __shared__ int sm[1824];
    const int tid = threadIdx.x, bid = blockIdx.x;

    if (bid < HH * NB) {
        // ---- pack x: int32 NCHW -> int8 NHWC, dword-packed transpose ----
        const int h = bid % HH, n = bid / HH;
        if (bid == 0 && tid < 32) ((int*)(xp + XP_BYTES))[tid] = 0;  // zero page
        #pragma unroll
        for (int it = 0; it < 7; ++it) {
            int j = tid + it * 256;                 // 1792 = 128 ci x 14 w4
            int ci = j / 14, w4 = j - ci * 14;
            const v4i v = *(const v4i*)(x + ((n * CI + ci) * HH + h) * WW + w4 * 4);
            int p = (v.x & 255) | ((v.y & 255) << 8) | ((v.z & 255) << 16) | (v.w << 24);
            sm[w4 * 130 + ci] = p;                  // [w4][ci], pad->conflict-lite
        }
        __syncthreads();
        int* xpd = (int*)xp + (n * HH + h) * (WW * CI / 4);
        #pragma unroll
        for (int it = 0; it < 7; ++it) {
            int o = tid + it * 256;                 // o = w*32 + ci4
            int w = o >> 5, ci4 = o & 31;
            int base = (w >> 2) * 130 + ci4 * 4;
            int sh = (w & 3) * 8;
            int d0 = sm[base], d1 = sm[base + 1], d2 = sm[base + 2], d3 = sm[base + 3];
            xpd[o] = ((d0 >> sh) & 0xff) | (((d1 >> sh) & 0xff) << 8) |
                     (((d2 >> sh) & 0xff) << 16) | ((d3 >> sh) << 24);
        }
    } else {
        // ---- pack w for one co + BG[co][9] ----
        const int co = bid - HH * NB;
        for (int j = tid; j < 1152; j += 256) sm[j] = wgt[co * 1152 + j];  // [ci][9]
        __syncthreads();
        for (int j = tid; j < 288; j += 256) {      // 288 = 9t x 2c64 x 4q x 4j4
            int j4 = j & 3, q = (j >> 2) & 3, c64 = (j >> 4) & 1, t = j >> 5;
            int ci = c64 * 64 + q * 16 + j4 * 4;
            int b0 = sm[(ci + 0) * 9 + t] & 255, b1 = sm[(ci + 1) * 9 + t] & 255;
            int b2 = sm[(ci + 2) * 9 + t] & 255, b3 = sm[(ci + 3) * 9 + t];
            ((int*)bp)[((t * 2 + c64) * 4 + q) * 1024 + co * 4 + j4] =
                b0 | (b1 << 8) | (b2 << 16) | (b3 << 24);
        }
        if (tid < 9) {                              // per-tap weight sums
            int s = 0;
            for (int ci = 0; ci < CI; ++ci) s += sm[ci * 9 + tid];
            sm[1152 + tid] = s;
        }
        __syncthreads();
        if (tid < 9) {                              // border-class -> BG
            int hc = tid / 3, wc = tid - hc * 3;
            int dlo = (hc == 0) ? 1 : 0, dhi = (hc == 2) ? 1 : 2;
            int clo = (wc == 0) ? 1 : 0, chi = (wc == 2) ? 1 : 2;
            int s = 0;
            for (int dr = dlo; dr <= dhi; ++dr)
                for (int dc = clo; dc <= chi; ++dc) s += sm[1152 + dr * 3 + dc];
            BG[co * 9 + tid] = bias[co] - (*zpi) * s;
        }
    }
}

// ---- main: block = 256 M x 64 co, 4 waves of 64 M x 64 co; barrier-free K ----
__global__ __launch_bounds__(256, 2) void qconv_mfma(
    const int8_t* __restrict__ xp, const int8_t* __restrict__ bp,
    const int* __restrict__ BG,
    const float* __restrict__ si, const float* __restrict__ sw,
    const float* __restrict__ so, const int* __restrict__ zpo,
    int* __restrict__ out)
{
    const int tid  = threadIdx.x, lane = tid & 63, wid = tid >> 6;
    const int quad = lane >> 4, lo16 = lane & 15;
    const int mbase  = blockIdx.x * 256 + wid * 64;
    const int coq    = blockIdx.y;
    const int cobase = coq * 64;

    __shared__ char smem[72 * 1024];         // B: 72 x 1KB units; epilogue aliases

    #pragma unroll
    for (int k = 0; k < 18; ++k) {           // stage B once (18 KB per wave)
        const int u = wid + 4 * k;
        __builtin_amdgcn_global_load_lds(
            (const __attribute__((address_space(1))) void*)
                (bp + ((u * 4 + coq) << 10) + lane * 16),
            (__attribute__((address_space(3))) void*)(smem + (u << 10)),
            16, 0, 0);
    }

    const int nS   = mbase / SPA;            // wave-uniform (64 | 3136)
    const int remS = mbase - nS * SPA;
    int r[4], hh[4], ww[4];
    #pragma unroll
    for (int k = 0; k < 4; ++k) {
        const int rm = remS + lo16 + 16 * k;
        hh[k] = rm / WW; ww[k] = rm - hh[k] * WW;
        r[k]  = mbase + lo16 + 16 * k;
    }
    const int aq = quad * 16;

    v4i acc[4][4];
    #pragma unroll
    for (int k = 0; k < 4; ++k)
        #pragma unroll
        for (int ct = 0; ct < 4; ++ct) acc[k][ct] = (v4i){0, 0, 0, 0};

    v4i aC[4][2], aN[4][2];
    #pragma unroll
    for (int k = 0; k < 4; ++k) {            // tap 0 (dr=0,dc=0): offset -57 rows
        const bool v = (hh[k] >= 1) && (ww[k] >= 1);
        const int o = v ? ((r[k] - WW - 1) << 7) + aq : XP_BYTES;
        aC[k][0] = *(const v4i*)(xp + o);
        aC[k][1] = *(const v4i*)(xp + o + 64);
    }
    __syncthreads();                          // B staged

    #pragma unroll
    for (int t = 0; t < 9; ++t) {
        if (t < 8) {                          // prefetch tap t+1
            const int tt = t + 1, dr = tt / 3, dc = tt - dr * 3;
            #pragma unroll
            for (int k = 0; k < 4; ++k) {
                const bool v = ((unsigned)(hh[k] + dr - 1) < HH) &&
                               ((unsigned)(ww[k] + dc - 1) < WW);
                const int o = v ? ((r[k] + (dr - 1) * WW + (dc - 1)) << 7) + aq
                               : XP_BYTES;
                aN[k][0] = *(const v4i*)(xp + o);
                aN[k][1] = *(const v4i*)(xp + o + 64);
            }
        }
        #pragma unroll
        for (int c = 0; c < 2; ++c) {
            const int ub = ((t * 2 + c) * 4 + quad) * 1024 + lo16 * 16;
            #pragma unroll
            for (int ct = 0; ct < 4; ++ct) {
                v4i b = *(const v4i*)(smem + ub + ct * 256);
                #pragma unroll
                for (int k = 0; k < 4; ++k)
                    acc[k][ct] = __builtin_amdgcn_mfma_i32_16x16x64_i8(
                        aC[k][c], b, acc[k][ct], 0, 0, 0);
            }
        }
        #pragma unroll
        for (int k = 0; k < 4; ++k) {
            aC[k][0] = aN[k][0]; aC[k][1] = aN[k][1];
        }
    }

    // ---- epilogue: requant + LDS transpose (aliased onto dead B) ----
    const float rs = (*si) * (*sw) / (*so);
    const float zo = (float)(*zpo);

    __syncthreads();                          // all waves done reading B
    int* lt = (int*)smem + wid * 4352;        // 64 co x 68 dwords per wave

    #pragma unroll
    for (int mt = 0; mt < 4; ++mt) {
        int cls[4];
        #pragma unroll
        for (int i = 0; i < 4; ++i) {
            const int ml = mt * 16 + quad * 4 + i;       // C/D row = quad*4+reg
            const int rm = remS + ml;
            const int h2 = rm / WW, w2 = rm - h2 * WW;
            const int hc = (h2 == 0) ? 0 : ((h2 == HH - 1) ? 2 : 1);
            const int wc = (w2 == 0) ? 0 : ((w2 == WW - 1) ? 2 : 1);
            cls[i] = hc * 3 + wc;
        }
        #pragma unroll
        for (int ct = 0; ct < 4; ++ct) {
            const int co = cobase + ct * 16 + lo16;      // C/D col = lane&15
            v4i vv;
            #pragma unroll
            for (int i = 0; i < 4; ++i) {
                int a = acc[mt][ct][i] + BG[co * 9 + cls[i]];
                float y = rintf((float)a * rs + zo);
                y = fminf(fmaxf(y, -128.f), 127.f);
                vv[i] = (int)y;
            }
            *(v4i*)(lt + (ct * 16 + lo16) * 68 + mt * 16 + quad * 4) = vv;
        }
    }
    // same-wave ds_write -> ds_read: in-order, no barrier

    #pragma unroll
    for (int cc = 0; cc < 16; ++cc) {
        const int col = cc * 4 + quad;                   // co_local 0..63
        const int m4  = lo16 * 4;
        v4i v = *(const v4i*)(lt + col * 68 + m4);
        const int oidx = (nS * CO + cobase + col) * SPA + remS + m4;
        *(v4i*)(out + oidx) = v;                         // 256-B runs, coalesced
    }
}

extern "C" void kernel_launch(void* const* d_in, const int* in_sizes, int n_in,
                              void* d_out, int out_size, void* d_ws, size_t ws_size,
                              hipStream_t stream) {
    const int*   x    = (const int*)d_in[0];
    const int*   wgt  = (const int*)d_in[1];
    const int*   bias = (const int*)d_in[2];
    const float* si   = (const float*)d_in[3];
    const float* sw   = (const float*)d_in[4];
    const float* so   = (const float*)d_in[5];
    const int*   zpi  = (const int*)d_in[6];
    const int*   zpo  = (const int*)d_in[7];
    int* out = (int*)d_out;

    int8_t* xp = (int8_t*)d_ws;                 // + 128-B zero page
    int8_t* bp = xp + XP_BYTES + 128;
    int*    bg = (int*)(bp + BP_BYTES);

    prep_kernel<<<HH * NB + CO, 256, 0, stream>>>(x, wgt, bias, zpi, xp, bp, bg);
    qconv_mfma<<<dim3(100352 / 256, CO / 64), 256, 0, stream>>>(
        xp, bp, bg, si, sw, so, zpo, out);
}